// Round 19
// baseline (25.779 us; speedup 1.0000x reference)
//
#include <hip/hip_runtime.h>
#include <math.h>

#define IMG 256
#define NFACE 1000
#define NFP 1024               // padded face count; 4 waves x 256 faces (4 rounds)
#define NWAVE 4
#define EPSF 1e-8f
#define LOG2E 1.44269504088896f
#define TCUT 16.0f             // drop contributions with u < -TCUT (<= 1.44*2^-16 each)
#define ACC_BREAK 25.0f        // once all lanes of a wave exceed: its tail < 2^-25
// Tile-center cull: max_tile u <= min_k c_k(center) + 3.5*sqrt(2)*LOG2E (=7.15)
#define CULL_M (-(TCUT + 7.15f))

// Static device scratch (graph-capture safe).
// g_soa: SoA for the lane-parallel cull (coalesced dword loads).
// g_cf:  AoS 3 x float4 per face for the walk (uniform scalar-addressed
//        dwordx4 loads). Faces >= NFACE self-reject (c2 = -1e9).
__device__ float g_soa[9][NFP];
__device__ float4 g_cf[NFP * 3];

// ---------------------------------------------------------------------------
// Kernel 1: per-face edge line coefficients (log2e-scaled), SoA + AoS.
// Also zeroes out[] (block 0). Degenerate faces (repeated vertex -> zero
// edge -> c==0 everywhere, face paints an infinite line band) need no
// special case under the center-distance cull.
// ---------------------------------------------------------------------------
__global__ __launch_bounds__(256) void k_coeff(const float* __restrict__ verts,
                                               const int* __restrict__ faces,
                                               const float* __restrict__ q,
                                               const float* __restrict__ t,
                                               const float* __restrict__ K,
                                               float* __restrict__ out) {
    int f = blockIdx.x * 256 + threadIdx.x;   // grid = 4 blocks -> f in [0,1024)
    if (blockIdx.x == 0 && threadIdx.x < IMG) out[threadIdx.x] = 0.f;
    if (f >= NFP) return;

    float c[9];
    if (f < NFACE) {
        float qw = q[0], qx = q[1], qy = q[2], qz = q[3];
        float qn = sqrtf(qw * qw + qx * qx + qy * qy + qz * qz + EPSF);
        qw /= qn; qx /= qn; qy /= qn; qz /= qn;
        float R00 = 1.f - 2.f * (qy * qy + qz * qz);
        float R01 = 2.f * (qx * qy - qw * qz);
        float R02 = 2.f * (qx * qz + qw * qy);
        float R10 = 2.f * (qx * qy + qw * qz);
        float R11 = 1.f - 2.f * (qx * qx + qz * qz);
        float R12 = 2.f * (qy * qz - qw * qx);
        float R20 = 2.f * (qx * qz - qw * qy);
        float R21 = 2.f * (qy * qz + qw * qx);
        float R22 = 1.f - 2.f * (qx * qx + qy * qy);
        float tx = t[0], ty = t[1], tz = t[2];
        float K00 = K[0], K02 = K[2], K11 = K[4], K12 = K[5];

        float X[3], Y[3];
#pragma unroll
        for (int k = 0; k < 3; ++k) {
            int vi = faces[f * 3 + k];
            float vx = verts[vi * 3 + 0];
            float vy = verts[vi * 3 + 1];
            float vz = verts[vi * 3 + 2];
            float cx = R00 * vx + R01 * vy + R02 * vz + tx;
            float cy = R10 * vx + R11 * vy + R12 * vz + ty;
            float cz = R20 * vx + R21 * vy + R22 * vz + tz;
            float z = cz + EPSF;
            X[k] = K00 * cx / z + K02;
            Y[k] = K11 * cy / z + K12;
        }

        float e01x = X[1] - X[0], e01y = Y[1] - Y[0];
        float e02x = X[2] - X[0], e02y = Y[2] - Y[0];
        float area2 = e01x * e02y - e01y * e02x;
        float s = (area2 >= 0.f) ? LOG2E : -LOG2E;

#pragma unroll
        for (int k = 0; k < 3; ++k) {
            int k1 = (k + 1) % 3;
            float ex = X[k1] - X[k];
            float ey = Y[k1] - Y[k];
            float inv = s / sqrtf(ex * ex + ey * ey + EPSF);
            c[k * 3 + 0] = -ey * inv;
            c[k * 3 + 1] = ex * inv;
            c[k * 3 + 2] = (ey * X[k] - ex * Y[k]) * inv;
        }
    } else {
        c[0] = 0.f; c[1] = 0.f; c[2] = -1e9f;
        c[3] = 0.f; c[4] = 0.f; c[5] = -1e9f;
        c[6] = 0.f; c[7] = 0.f; c[8] = -1e9f;
    }

#pragma unroll
    for (int k = 0; k < 9; ++k) g_soa[k][f] = c[k];
    g_cf[f * 3 + 0] = make_float4(c[0], c[1], c[2], 0.f);
    g_cf[f * 3 + 1] = make_float4(c[3], c[4], c[5], 0.f);
    g_cf[f * 3 + 2] = make_float4(c[6], c[7], c[8], 0.f);
}

// ---------------------------------------------------------------------------
// Kernel 2: fused render+loss. R16's structure and launch shape (best known)
// with ONE change in the survivor walk: instead of broadcasting the culling
// lane's 9 coefficient registers via v_readlane (9 readlane + ~9 v_mov issue
// cycles per survivor - R18 showed this is issue-bound), the wave-uniform
// survivor index (forced to SGPR via readfirstlane) addresses g_cf directly:
// 3 x dwordx4 uniform loads, latency hidden by the 2-wide unroll. Results
// arrive in VGPRs, so the FMAs hit no SGPR-operand limit.
// ---------------------------------------------------------------------------
__global__ __launch_bounds__(256) void k_main(const float* __restrict__ image_ref,
                                              float* __restrict__ out) {
    const int tid = threadIdx.x;
    const int wave = tid >> 6;
    const int lane = tid & 63;
    const int x0 = blockIdx.x * 8, y0 = blockIdx.y * 8;
    const int col = x0 + (lane & 7);
    const int row = y0 + (lane >> 3);
    const float px = col + 0.5f;
    const float py = row + 0.5f;
    const float tcx = x0 + 4.0f;   // pixel centers span +0.5..+7.5
    const float tcy = y0 + 4.0f;

    __shared__ float s_acc[NWAVE][64];

    float acc = 0.f;
    const int wbase = wave * 256;
    for (int r = 0; r < 4; ++r) {
        const int fb = wbase + r * 64;
        const int f = fb + lane;
        float l0 = g_soa[0][f], l1 = g_soa[1][f], l2 = g_soa[2][f];
        float l3 = g_soa[3][f], l4 = g_soa[4][f], l5 = g_soa[5][f];
        float l6 = g_soa[6][f], l7 = g_soa[7][f], l8 = g_soa[8][f];
        float m = fminf(fminf(fmaf(tcx, l0, fmaf(tcy, l1, l2)),
                              fmaf(tcx, l3, fmaf(tcy, l4, l5))),
                        fmaf(tcx, l6, fmaf(tcy, l7, l8)));
        unsigned long long msk = __ballot(m > CULL_M);
        float p = 1.f;                      // running product of (1 + 2^-|u|)
        while (msk) {
            int s0 = __ffsll((unsigned long long)msk) - 1;   // uniform
            msk &= msk - 1;
            bool has1 = (msk != 0);                          // uniform
            int s1 = has1 ? (__ffsll((unsigned long long)msk) - 1) : s0;
            msk &= msk - 1;
            float g1 = has1 ? 1.f : 0.f;

            // Force SGPR; 3 uniform dwordx4 loads per survivor.
            int i0 = __builtin_amdgcn_readfirstlane(fb + s0) * 3;
            int i1 = __builtin_amdgcn_readfirstlane(fb + s1) * 3;
            float4 aA = g_cf[i0 + 0], bA = g_cf[i0 + 1], cA = g_cf[i0 + 2];
            float4 aB = g_cf[i1 + 0], bB = g_cf[i1 + 1], cB = g_cf[i1 + 2];

            float u0 = fminf(fminf(fmaf(px, aA.x, fmaf(py, aA.y, aA.z)),
                                   fmaf(px, bA.x, fmaf(py, bA.y, bA.z))),
                             fmaf(px, cA.x, fmaf(py, cA.y, cA.z)));
            float u1 = fminf(fminf(fmaf(px, aB.x, fmaf(py, aB.y, aB.z)),
                                   fmaf(px, bB.x, fmaf(py, bB.y, bB.z))),
                             fmaf(px, cB.x, fmaf(py, cB.y, cB.z)));

            acc += fmaxf(u0, 0.f) + fmaxf(u1, 0.f) * g1;
            float e0 = __builtin_amdgcn_exp2f(-fabsf(u0));
            float e1 = __builtin_amdgcn_exp2f(-fabsf(u1)) * g1;
            p = fmaf(p, e0, p);             // p *= (1 + e0)
            p = fmaf(p, e1, p);             // p *= (1 + e1)
        }
        acc += __builtin_amdgcn_logf(p);    // one log2 per round
        if (__all(acc > ACC_BREAK)) break;  // wave's remaining tail < 2^-25
    }

    // ---- combine waves, sil, sqdiff, row-reduce, atomic row partial ----
    s_acc[wave][lane] = acc;
    __syncthreads();
    if (wave == 0) {
        float tot = s_acc[0][lane] + s_acc[1][lane] +
                    s_acc[2][lane] + s_acc[3][lane];
        float sil = 1.f - __builtin_amdgcn_exp2f(-tot);
        float d = sil - image_ref[row * IMG + col];
        float v = d * d;
        v += __shfl_xor(v, 1);   // sum over the 8 cols of this tile row
        v += __shfl_xor(v, 2);
        v += __shfl_xor(v, 4);
        if ((lane & 7) == 0) atomicAdd(&out[row], v * (1.f / 256.f));
    }
}

// ---------------------------------------------------------------------------
extern "C" void kernel_launch(void* const* d_in, const int* in_sizes, int n_in,
                              void* d_out, int out_size, void* d_ws, size_t ws_size,
                              hipStream_t stream) {
    const float* verts = (const float*)d_in[0];      // (1,1000,3) f32
    const int* faces = (const int*)d_in[1];          // (1,1000,3) i32
    const float* q = (const float*)d_in[2];          // (4,) f32
    const float* t = (const float*)d_in[3];          // (3,) f32
    const float* K = (const float*)d_in[4];          // (3,3) f32
    const float* image_ref = (const float*)d_in[5];  // (256,256) f32
    float* out = (float*)d_out;                      // (256,) f32

    k_coeff<<<NFP / 256, 256, 0, stream>>>(verts, faces, q, t, K, out);
    k_main<<<dim3(IMG / 8, IMG / 8), 256, 0, stream>>>(image_ref, out);
}

// Round 20
// 20.825 us; speedup vs baseline: 1.2379x; 1.2379x over previous
//
#include <hip/hip_runtime.h>
#include <math.h>

#define IMG 256
#define NFACE 1000
#define NFP 1024               // padded face count; 4 waves x 256 faces (4 rounds)
#define NWAVE 4
#define EPSF 1e-8f
#define LOG2E 1.44269504088896f
#define TCUT 16.0f             // drop contributions with u < -TCUT (<= 1.44*2^-16 each)
#define ACC_BREAK 25.0f        // acc lower bound > 25 -> dropped tail < 2^-25
#define RSLACK 7.15f           // 3.5*sqrt(2)*LOG2E: |c(px)-c(center)| bound in-tile

// Static device scratch (graph-capture safe). SoA: 9 arrays of 1024 floats.
// Faces >= NFACE are self-rejecting pads (c2 = -1e9 -> never survive cull).
__device__ float g_soa[9][NFP];

// Broadcast lane s's register to all lanes (uniform s -> v_readlane).
__device__ __forceinline__ float bcast(float x, int s) {
    return __uint_as_float(__builtin_amdgcn_readlane(__float_as_uint(x), s));
}

// ---------------------------------------------------------------------------
// Kernel 1: per-face edge line coefficients (log2e-scaled), SoA.
// Also zeroes out[] (block 0). Degenerate faces (repeated vertex -> zero
// edge -> c==0 everywhere, face paints an infinite line band) need no
// special case under the line-distance cull.
// ---------------------------------------------------------------------------
__global__ __launch_bounds__(256) void k_coeff(const float* __restrict__ verts,
                                               const int* __restrict__ faces,
                                               const float* __restrict__ q,
                                               const float* __restrict__ t,
                                               const float* __restrict__ K,
                                               float* __restrict__ out) {
    int f = blockIdx.x * 256 + threadIdx.x;   // grid = 4 blocks -> f in [0,1024)
    if (blockIdx.x == 0 && threadIdx.x < IMG) out[threadIdx.x] = 0.f;
    if (f >= NFP) return;

    float c[9];
    if (f < NFACE) {
        float qw = q[0], qx = q[1], qy = q[2], qz = q[3];
        float qn = sqrtf(qw * qw + qx * qx + qy * qy + qz * qz + EPSF);
        qw /= qn; qx /= qn; qy /= qn; qz /= qn;
        float R00 = 1.f - 2.f * (qy * qy + qz * qz);
        float R01 = 2.f * (qx * qy - qw * qz);
        float R02 = 2.f * (qx * qz + qw * qy);
        float R10 = 2.f * (qx * qy + qw * qz);
        float R11 = 1.f - 2.f * (qx * qx + qz * qz);
        float R12 = 2.f * (qy * qz - qw * qx);
        float R20 = 2.f * (qx * qz - qw * qy);
        float R21 = 2.f * (qy * qz + qw * qx);
        float R22 = 1.f - 2.f * (qx * qx + qy * qy);
        float tx = t[0], ty = t[1], tz = t[2];
        float K00 = K[0], K02 = K[2], K11 = K[4], K12 = K[5];

        float X[3], Y[3];
#pragma unroll
        for (int k = 0; k < 3; ++k) {
            int vi = faces[f * 3 + k];
            float vx = verts[vi * 3 + 0];
            float vy = verts[vi * 3 + 1];
            float vz = verts[vi * 3 + 2];
            float cx = R00 * vx + R01 * vy + R02 * vz + tx;
            float cy = R10 * vx + R11 * vy + R12 * vz + ty;
            float cz = R20 * vx + R21 * vy + R22 * vz + tz;
            float z = cz + EPSF;
            X[k] = K00 * cx / z + K02;
            Y[k] = K11 * cy / z + K12;
        }

        float e01x = X[1] - X[0], e01y = Y[1] - Y[0];
        float e02x = X[2] - X[0], e02y = Y[2] - Y[0];
        float area2 = e01x * e02y - e01y * e02x;
        float s = (area2 >= 0.f) ? LOG2E : -LOG2E;

#pragma unroll
        for (int k = 0; k < 3; ++k) {
            int k1 = (k + 1) % 3;
            float ex = X[k1] - X[k];
            float ey = Y[k1] - Y[k];
            float inv = s / sqrtf(ex * ex + ey * ey + EPSF);
            c[k * 3 + 0] = -ey * inv;
            c[k * 3 + 1] = ex * inv;
            c[k * 3 + 2] = (ey * X[k] - ex * Y[k]) * inv;
        }
    } else {
        c[0] = 0.f; c[1] = 0.f; c[2] = -1e9f;
        c[3] = 0.f; c[4] = 0.f; c[5] = -1e9f;
        c[6] = 0.f; c[7] = 0.f; c[8] = -1e9f;
    }

#pragma unroll
    for (int k = 0; k < 9; ++k) g_soa[k][f] = c[k];
}

// ---------------------------------------------------------------------------
// Kernel 2: fused render+loss. R16's walk (readlane + product, best known)
// with three conservative work cuts (R19 post-mortem: hot wave = boundary
// wave walking ~250 survivors, inflated 1.45x by the old cull's radius
// slack; center waves' round-1 walks wasted ~60 survivors before breaking):
//  (1) EXACT corner cull: max over tile of edge func c_k is
//      c_k(center) + 3.5*(|cx|+|cy|) (linear, corners at +-3.5). Keep face
//      iff min_k cornermax > -TCUT. No 7.15 slack -> band survivors x0.69.
//  (2) Whole-tile interior skip: S_tile = sum over ALL 1000 faces of
//      max(m_center - 7.15, 0) <= acc(px) for every tile pixel. If
//      S_tile > 25, sil == 1.0f exactly -> no walk at all (center tiles).
//  (3) In-walk break every 8 survivors (mid tiles stop mid-round).
// ---------------------------------------------------------------------------
__global__ __launch_bounds__(256) void k_main(const float* __restrict__ image_ref,
                                              float* __restrict__ out) {
    const int tid = threadIdx.x;
    const int wave = tid >> 6;
    const int lane = tid & 63;
    const int x0 = blockIdx.x * 8, y0 = blockIdx.y * 8;
    const int col = x0 + (lane & 7);
    const int row = y0 + (lane >> 3);
    const float px = col + 0.5f;
    const float py = row + 0.5f;
    const float tcx = x0 + 4.0f;   // pixel centers span +0.5..+7.5
    const float tcy = y0 + 4.0f;

    __shared__ float s_acc[NWAVE][64];
    __shared__ float s_S[NWAVE];

    const int wbase = wave * 256;

    // ---- load all 4 rounds' coefficients upfront (static-indexed regs) ----
    float l[4][9];
#pragma unroll
    for (int r = 0; r < 4; ++r) {
        const int f = wbase + r * 64 + lane;
#pragma unroll
        for (int k = 0; k < 9; ++k) l[r][k] = g_soa[k][f];
    }

    // ---- cull all rounds (exact corner test) + acc lower bound ----
    unsigned long long msk0 = 0, msk1 = 0, msk2 = 0, msk3 = 0;
    float slb = 0.f;   // per-lane sum of max(m_center - RSLACK, 0)
#pragma unroll
    for (int r = 0; r < 4; ++r) {
        float c0 = fmaf(tcx, l[r][0], fmaf(tcy, l[r][1], l[r][2]));
        float c1 = fmaf(tcx, l[r][3], fmaf(tcy, l[r][4], l[r][5]));
        float c2 = fmaf(tcx, l[r][6], fmaf(tcy, l[r][7], l[r][8]));
        float mc = fminf(fminf(c0, c1), c2);
        slb += fmaxf(mc - RSLACK, 0.f);
        float e0 = c0 + 3.5f * (fabsf(l[r][0]) + fabsf(l[r][1]));
        float e1 = c1 + 3.5f * (fabsf(l[r][3]) + fabsf(l[r][4]));
        float e2 = c2 + 3.5f * (fabsf(l[r][6]) + fabsf(l[r][7]));
        float mx = fminf(fminf(e0, e1), e2);   // = max over tile of u (exact)
        unsigned long long mm = __ballot(mx > -TCUT);
        if (r == 0) msk0 = mm;
        else if (r == 1) msk1 = mm;
        else if (r == 2) msk2 = mm;
        else msk3 = mm;
    }
#pragma unroll
    for (int o = 1; o < 64; o <<= 1) slb += __shfl_xor(slb, o);
    if (lane == 0) s_S[wave] = slb;
    __syncthreads();
    const float S_tile = s_S[0] + s_S[1] + s_S[2] + s_S[3];

    float acc;
    if (S_tile > ACC_BREAK) {
        // every pixel's true acc >= S_tile > 25 -> sil == 1.0f exactly
        acc = 8.f;   // 4 waves x 8 = 32 -> sil = 1 - 2^-32 == 1.0f
    } else {
        acc = 0.f;
        int cnt = 0;
        bool done = false;
#pragma unroll
        for (int r = 0; r < 4; ++r) {
            if (!done) {
                unsigned long long msk = (r == 0) ? msk0 : (r == 1) ? msk1
                                       : (r == 2) ? msk2 : msk3;
                float p = 1.f;              // running product of (1 + 2^-|u|)
                while (msk) {
                    int s = __ffsll((unsigned long long)msk) - 1;  // uniform
                    msk &= msk - 1;
                    float a0 = bcast(l[r][0], s), a1 = bcast(l[r][1], s), a2 = bcast(l[r][2], s);
                    float b0 = bcast(l[r][3], s), b1 = bcast(l[r][4], s), b2 = bcast(l[r][5], s);
                    float c0 = bcast(l[r][6], s), c1 = bcast(l[r][7], s), c2 = bcast(l[r][8], s);
                    float u = fminf(fminf(fmaf(px, a0, fmaf(py, a1, a2)),
                                          fmaf(px, b0, fmaf(py, b1, b2))),
                                    fmaf(px, c0, fmaf(py, c1, c2)));
                    acc += fmaxf(u, 0.f);
                    float e = __builtin_amdgcn_exp2f(-fabsf(u));
                    p = fmaf(p, e, p);      // p *= (1 + e)
                    if (((++cnt) & 7) == 0 && __all(acc > ACC_BREAK)) {
                        done = true;        // dropped tail >= 0 -> < 2^-25
                        break;
                    }
                }
                acc += __builtin_amdgcn_logf(p);    // one log2 per round
                if (__all(acc > ACC_BREAK)) done = true;
            }
        }
    }

    // ---- combine waves, sil, sqdiff, row-reduce, atomic row partial ----
    s_acc[wave][lane] = acc;
    __syncthreads();
    if (wave == 0) {
        float tot = s_acc[0][lane] + s_acc[1][lane] +
                    s_acc[2][lane] + s_acc[3][lane];
        float sil = 1.f - __builtin_amdgcn_exp2f(-tot);
        float d = sil - image_ref[row * IMG + col];
        float v = d * d;
        v += __shfl_xor(v, 1);   // sum over the 8 cols of this tile row
        v += __shfl_xor(v, 2);
        v += __shfl_xor(v, 4);
        if ((lane & 7) == 0) atomicAdd(&out[row], v * (1.f / 256.f));
    }
}

// ---------------------------------------------------------------------------
extern "C" void kernel_launch(void* const* d_in, const int* in_sizes, int n_in,
                              void* d_out, int out_size, void* d_ws, size_t ws_size,
                              hipStream_t stream) {
    const float* verts = (const float*)d_in[0];      // (1,1000,3) f32
    const int* faces = (const int*)d_in[1];          // (1,1000,3) i32
    const float* q = (const float*)d_in[2];          // (4,) f32
    const float* t = (const float*)d_in[3];          // (3,) f32
    const float* K = (const float*)d_in[4];          // (3,3) f32
    const float* image_ref = (const float*)d_in[5];  // (256,256) f32
    float* out = (float*)d_out;                      // (256,) f32

    k_coeff<<<NFP / 256, 256, 0, stream>>>(verts, faces, q, t, K, out);
    k_main<<<dim3(IMG / 8, IMG / 8), 256, 0, stream>>>(image_ref, out);
}

// Round 21
// 20.634 us; speedup vs baseline: 1.2493x; 1.0093x over previous
//
#include <hip/hip_runtime.h>
#include <math.h>

#define IMG 256
#define NFACE 1000
#define NFP 1024               // padded face count; 4 waves x 256 faces (4 rounds)
#define NWAVE 4
#define CAP 1024               // survivor list capacity: cnt <= 1000, cntp <= 1024
#define EPSF 1e-8f
#define LOG2E 1.44269504088896f
#define TCUT 16.0f             // drop contributions with u < -TCUT (<= 1.44*2^-16 each)
#define ACC_BREAK 25.0f        // acc lower bound > 25 -> error < 2^-25
#define RSLACK 7.15f           // 3.5*sqrt(2)*LOG2E: |c(px)-c(center)| in-tile bound

// Static device scratch (graph-capture safe). SoA: 9 arrays of 1024 floats.
// Faces >= NFACE are self-rejecting pads (c2 = -1e9 -> never survive cull).
__device__ float g_soa[9][NFP];

// ---------------------------------------------------------------------------
// Kernel 1: per-face edge line coefficients (log2e-scaled), SoA.
// Also zeroes out[] (block 0). Degenerate faces (repeated vertex -> zero
// edge -> c==0 everywhere, face paints an infinite line band) need no
// special case under the line-distance cull.
// ---------------------------------------------------------------------------
__global__ __launch_bounds__(256) void k_coeff(const float* __restrict__ verts,
                                               const int* __restrict__ faces,
                                               const float* __restrict__ q,
                                               const float* __restrict__ t,
                                               const float* __restrict__ K,
                                               float* __restrict__ out) {
    int f = blockIdx.x * 256 + threadIdx.x;   // grid = 4 blocks -> f in [0,1024)
    if (blockIdx.x == 0 && threadIdx.x < IMG) out[threadIdx.x] = 0.f;
    if (f >= NFP) return;

    float c[9];
    if (f < NFACE) {
        float qw = q[0], qx = q[1], qy = q[2], qz = q[3];
        float qn = sqrtf(qw * qw + qx * qx + qy * qy + qz * qz + EPSF);
        qw /= qn; qx /= qn; qy /= qn; qz /= qn;
        float R00 = 1.f - 2.f * (qy * qy + qz * qz);
        float R01 = 2.f * (qx * qy - qw * qz);
        float R02 = 2.f * (qx * qz + qw * qy);
        float R10 = 2.f * (qx * qy + qw * qz);
        float R11 = 1.f - 2.f * (qx * qx + qz * qz);
        float R12 = 2.f * (qy * qz - qw * qx);
        float R20 = 2.f * (qx * qz - qw * qy);
        float R21 = 2.f * (qy * qz + qw * qx);
        float R22 = 1.f - 2.f * (qx * qx + qy * qy);
        float tx = t[0], ty = t[1], tz = t[2];
        float K00 = K[0], K02 = K[2], K11 = K[4], K12 = K[5];

        float X[3], Y[3];
#pragma unroll
        for (int k = 0; k < 3; ++k) {
            int vi = faces[f * 3 + k];
            float vx = verts[vi * 3 + 0];
            float vy = verts[vi * 3 + 1];
            float vz = verts[vi * 3 + 2];
            float cx = R00 * vx + R01 * vy + R02 * vz + tx;
            float cy = R10 * vx + R11 * vy + R12 * vz + ty;
            float cz = R20 * vx + R21 * vy + R22 * vz + tz;
            float z = cz + EPSF;
            X[k] = K00 * cx / z + K02;
            Y[k] = K11 * cy / z + K12;
        }

        float e01x = X[1] - X[0], e01y = Y[1] - Y[0];
        float e02x = X[2] - X[0], e02y = Y[2] - Y[0];
        float area2 = e01x * e02y - e01y * e02x;
        float s = (area2 >= 0.f) ? LOG2E : -LOG2E;

#pragma unroll
        for (int k = 0; k < 3; ++k) {
            int k1 = (k + 1) % 3;
            float ex = X[k1] - X[k];
            float ey = Y[k1] - Y[k];
            float inv = s / sqrtf(ex * ex + ey * ey + EPSF);
            c[k * 3 + 0] = -ey * inv;
            c[k * 3 + 1] = ex * inv;
            c[k * 3 + 2] = (ey * X[k] - ex * Y[k]) * inv;
        }
    } else {
        c[0] = 0.f; c[1] = 0.f; c[2] = -1e9f;
        c[3] = 0.f; c[4] = 0.f; c[5] = -1e9f;
        c[6] = 0.f; c[7] = 0.f; c[8] = -1e9f;
    }

#pragma unroll
    for (int k = 0; k < 9; ++k) g_soa[k][f] = c[k];
}

// ---------------------------------------------------------------------------
// Kernel 2: fused render+loss, LANE-PARALLEL face walk (R20 post-mortem:
// five serial-walk variants all ~21 us; the serialization itself was the
// cost - hot wave 250 survivors x ~90 cy. Post-cull work is only ~3.8M
// pair-evals: sub-us if lane-parallel).
//  Phase A (per wave, 4 rounds): exact corner cull + S_tile lower bound
//    (as R20); survivors' 9 coeffs appended from registers to a block-shared
//    LDS list (CAP=1024 >= any cnt: no overflow path). Pad to x32 with
//    zero-contribution sentinels.
//  Phase B: wave = 8 px x 8 faces. Wave w takes face-group j = w, w+4, ...;
//    per j: 3 broadcast ds_read_b128 (8 faces), then 8 unrolled pixel-rows
//    of 6FMA+min3+exp2+fmac into acc[g], p[g] - no ffs, no readlane, no
//    serial chain. p <= 2^32 (<=32 factors <= 2): single flush at end.
//    Reduce over face-lanes (shfl_xor 8/16/32), cross-wave via LDS.
//  S_tile > 25 -> sil == 1.0 exactly: skip walk (replaces ACC_BREAK).
// ---------------------------------------------------------------------------
__global__ __launch_bounds__(256) void k_main(const float* __restrict__ image_ref,
                                              float* __restrict__ out) {
    const int tid = threadIdx.x;
    const int wave = tid >> 6;
    const int lane = tid & 63;
    const int x0 = blockIdx.x * 8, y0 = blockIdx.y * 8;
    const float tcx = x0 + 4.0f;   // pixel centers span +0.5..+7.5
    const float tcy = y0 + 4.0f;

    __shared__ float4 s_cf[CAP * 3];    // 48 KB survivor coeff list
    __shared__ float s_acc[NWAVE][64];
    __shared__ float s_S[NWAVE];
    __shared__ int s_cnt;

    if (tid == 0) s_cnt = 0;
    __syncthreads();

    // ---- Phase A: cull (exact corner test) + S_tile bound + append ----
    const int wbase = wave * 256;
    float slb = 0.f;
    for (int r = 0; r < 4; ++r) {
        const int f = wbase + r * 64 + lane;
        float l0 = g_soa[0][f], l1 = g_soa[1][f], l2 = g_soa[2][f];
        float l3 = g_soa[3][f], l4 = g_soa[4][f], l5 = g_soa[5][f];
        float l6 = g_soa[6][f], l7 = g_soa[7][f], l8 = g_soa[8][f];
        float c0 = fmaf(tcx, l0, fmaf(tcy, l1, l2));
        float c1 = fmaf(tcx, l3, fmaf(tcy, l4, l5));
        float c2 = fmaf(tcx, l6, fmaf(tcy, l7, l8));
        float mc = fminf(fminf(c0, c1), c2);
        slb += fmaxf(mc - RSLACK, 0.f);
        float e0 = c0 + 3.5f * (fabsf(l0) + fabsf(l1));
        float e1 = c1 + 3.5f * (fabsf(l3) + fabsf(l4));
        float e2 = c2 + 3.5f * (fabsf(l6) + fabsf(l7));
        bool hit = (fminf(fminf(e0, e1), e2) > -TCUT);  // exact max-over-tile
        unsigned long long msk = __ballot(hit);
        int n = __popcll(msk);
        int base = 0;
        if (lane == 0) base = atomicAdd(&s_cnt, n);
        base = __builtin_amdgcn_readfirstlane(base);
        int pos = base + __popcll(msk & ((1ull << lane) - 1ull));
        if (hit) {
            s_cf[pos * 3 + 0] = make_float4(l0, l1, l2, 0.f);
            s_cf[pos * 3 + 1] = make_float4(l3, l4, l5, 0.f);
            s_cf[pos * 3 + 2] = make_float4(l6, l7, l8, 0.f);
        }
    }
#pragma unroll
    for (int o = 1; o < 64; o <<= 1) slb += __shfl_xor(slb, o);
    if (lane == 0) s_S[wave] = slb;
    __syncthreads();

    const int cnt = s_cnt;
    const int cntp = (cnt + 31) & ~31;          // multiple of 32 (<= 1024)
    if (tid < cntp - cnt) {                     // zero-contribution sentinels
        int ppos = cnt + tid;
        s_cf[ppos * 3 + 0] = make_float4(0.f, 0.f, -1e9f, 0.f);
        s_cf[ppos * 3 + 1] = make_float4(0.f, 0.f, -1e9f, 0.f);
        s_cf[ppos * 3 + 2] = make_float4(0.f, 0.f, -1e9f, 0.f);
    }
    __syncthreads();
    const float S_tile = s_S[0] + s_S[1] + s_S[2] + s_S[3];

    // ---- Phase B: lane-parallel walk (8 px x 8 faces per wave) ----
    if (S_tile <= ACC_BREAK) {
        const int fs = lane >> 3;      // face slot 0..7
        const int ii = lane & 7;       // tile column 0..7
        const float pxc = x0 + ii + 0.5f;
        float acc[8], p[8];
#pragma unroll
        for (int g = 0; g < 8; ++g) { acc[g] = 0.f; p[g] = 1.f; }

        const int nj = cntp >> 3;      // face groups (multiple of 4)
        for (int j = wave; j < nj; j += 4) {
            const int base = (j * 8 + fs) * 3;
            float4 A = s_cf[base + 0];
            float4 B = s_cf[base + 1];
            float4 C = s_cf[base + 2];
#pragma unroll
            for (int g = 0; g < 8; ++g) {
                float pyc = y0 + g + 0.5f;
                float u = fminf(fminf(fmaf(pxc, A.x, fmaf(pyc, A.y, A.z)),
                                      fmaf(pxc, B.x, fmaf(pyc, B.y, B.z))),
                                fmaf(pxc, C.x, fmaf(pyc, C.y, C.z)));
                acc[g] += fmaxf(u, 0.f);
                float e = __builtin_amdgcn_exp2f(-fabsf(u));
                p[g] = fmaf(p[g], e, p[g]);   // p *= (1 + e), <= 2^32 total
            }
        }
#pragma unroll
        for (int g = 0; g < 8; ++g) {
            float a = acc[g] + __builtin_amdgcn_logf(p[g]);
            a += __shfl_xor(a, 8);
            a += __shfl_xor(a, 16);
            a += __shfl_xor(a, 32);           // reduced over the 8 face-lanes
            if (fs == g) s_acc[wave][g * 8 + ii] = a;   // static index
        }
    }
    __syncthreads();

    // ---- combine waves, sil, sqdiff, row-reduce, atomic row partial ----
    if (wave == 0) {
        const int col = x0 + (lane & 7);
        const int row = y0 + (lane >> 3);
        float tot = (S_tile > ACC_BREAK)
                        ? 32.f                 // sil == 1.0f exactly
                        : (s_acc[0][lane] + s_acc[1][lane] +
                           s_acc[2][lane] + s_acc[3][lane]);
        float sil = 1.f - __builtin_amdgcn_exp2f(-tot);
        float d = sil - image_ref[row * IMG + col];
        float v = d * d;
        v += __shfl_xor(v, 1);   // sum over the 8 cols of this tile row
        v += __shfl_xor(v, 2);
        v += __shfl_xor(v, 4);
        if ((lane & 7) == 0) atomicAdd(&out[row], v * (1.f / 256.f));
    }
}

// ---------------------------------------------------------------------------
extern "C" void kernel_launch(void* const* d_in, const int* in_sizes, int n_in,
                              void* d_out, int out_size, void* d_ws, size_t ws_size,
                              hipStream_t stream) {
    const float* verts = (const float*)d_in[0];      // (1,1000,3) f32
    const int* faces = (const int*)d_in[1];          // (1,1000,3) i32
    const float* q = (const float*)d_in[2];          // (4,) f32
    const float* t = (const float*)d_in[3];          // (3,) f32
    const float* K = (const float*)d_in[4];          // (3,3) f32
    const float* image_ref = (const float*)d_in[5];  // (256,256) f32
    float* out = (float*)d_out;                      // (256,) f32

    k_coeff<<<NFP / 256, 256, 0, stream>>>(verts, faces, q, t, K, out);
    k_main<<<dim3(IMG / 8, IMG / 8), 256, 0, stream>>>(image_ref, out);
}